// Round 7
// baseline (43.512 us; speedup 1.0000x reference)
//
#include <hip/hip_runtime.h>

#define PPB 4  // waves per 256-thread block (K2)

typedef float v2f __attribute__((ext_vector_type(2)));

__device__ __forceinline__ float frcp(float x) { return __builtin_amdgcn_rcpf(x); }

__device__ __forceinline__ v2f vfma2(v2f a, v2f b, v2f c) {
#if __has_builtin(__builtin_elementwise_fma)
  return __builtin_elementwise_fma(a, b, c);
#else
  v2f d; d.x = fmaf(a.x, b.x, c.x); d.y = fmaf(a.y, b.y, c.y); return d;
#endif
}
__device__ __forceinline__ v2f vmul2(v2f a, v2f b) { return a * b; }
__device__ __forceinline__ v2f vadd2(v2f a, v2f b) { return a + b; }
__device__ __forceinline__ v2f bc(float x) { v2f p; p.x = x; p.y = x; return p; }

// packed FastGRNN gate update (2 independent recurrences per lane) — K2 only
__device__ __forceinline__ v2f gate2(v2f pre, v2f h, v2f bgB, v2f KB, v2f nzgB,
                                     v2f AB, bool first) {
  v2f a = vadd2(pre, bgB);
  v2f s; s.x = __expf(-a.x); s.y = __expf(-a.y);
  v2f one = bc(1.f);
  v2f zd = vadd2(s, one);
  v2f z; z.x = frcp(zd.x); z.y = frcp(zd.y);
  v2f u = vmul2(vmul2(s, s), KB);
  v2f cd = vadd2(u, one);
  v2f cr; cr.x = frcp(cd.x); cr.y = frcp(cd.y);
  v2f cc = vfma2(cr, bc(2.f), bc(-1.f));
  v2f m = vfma2(z, nzgB, AB);
  v2f mc = vmul2(m, cc);
  return first ? mc : vfma2(z, h, mc);
}

// ---------------- Kernel A: level-1, register-resident recurrences ----------------
// Block = (mode, b, window-pair wp). 224 recurrences (2 windows x 112), one per
// lane; h[8] lives in registers; U1/biases are wave-uniform (SGPRs). wx staged
// in LDS once, computed cooperatively from the pixel tile.
__global__ __launch_bounds__(256, 4) void l1_kernel(
    const float* __restrict__ inp, const float* __restrict__ W1,
    const float* __restrict__ U1, const float* __restrict__ bg1,
    const float* __restrict__ bu1, const float* __restrict__ zeta1,
    const float* __restrict__ nu1, float* __restrict__ hrowg,
    float* __restrict__ hcolg) {
  constexpr int ST = 98;  // wx row stride (floats): 12*8 + 2 -> 2-way banked b64

  __shared__ float w1s[128];
  __shared__ float wxs[112 * ST];  // 43.9 KB

  const int tid = threadIdx.x;
  const int bid = blockIdx.x;
  const bool isrow = bid < 448;
  const int v = isrow ? bid : bid - 448;
  const int b = v / 14, wp = v % 14;
  const int base4 = 8 * wp;                 // 4 * w0, w0 = 2*wp
  const int span = (wp == 13) ? 8 : 12;     // pixel columns covered

  if (tid < 32) ((float4*)w1s)[tid] = ((const float4*)W1)[tid];
  __syncthreads();

  // ---- wx phase: 1344 pixel slots, each -> 8-float GEMV into LDS ----
  for (int p = tid; p < 1344; p += 256) {
    int q, s;
    if (isrow) { q = p / 12;  s = p % 12; }   // q = y, s = xx
    else       { q = p % 112; s = p / 112; }  // q = x, s = yy
    if (s < span) {
      const float* px = isrow
          ? inp + ((size_t)(b * 112 + q) * 112 + base4 + s) * 16
          : inp + ((size_t)(b * 112 + base4 + s) * 112 + q) * 16;
      float4 x0 = ((const float4*)px)[0], x1 = ((const float4*)px)[1],
             x2 = ((const float4*)px)[2], x3 = ((const float4*)px)[3];
      float xr[16] = {x0.x, x0.y, x0.z, x0.w, x1.x, x1.y, x1.z, x1.w,
                      x2.x, x2.y, x2.z, x2.w, x3.x, x3.y, x3.z, x3.w};
      float a0 = 0.f, a1 = 0.f, a2 = 0.f, a3 = 0.f,
            a4 = 0.f, a5 = 0.f, a6 = 0.f, a7 = 0.f;
#pragma unroll
      for (int ci = 0; ci < 16; ++ci) {
        float4 wL = *(const float4*)&w1s[ci * 8];
        float4 wH = *(const float4*)&w1s[ci * 8 + 4];
        a0 = fmaf(xr[ci], wL.x, a0); a1 = fmaf(xr[ci], wL.y, a1);
        a2 = fmaf(xr[ci], wL.z, a2); a3 = fmaf(xr[ci], wL.w, a3);
        a4 = fmaf(xr[ci], wH.x, a4); a5 = fmaf(xr[ci], wH.y, a5);
        a6 = fmaf(xr[ci], wH.z, a6); a7 = fmaf(xr[ci], wH.w, a7);
      }
      float* wd = &wxs[q * ST + s * 8];
      ((float2*)wd)[0] = float2{a0, a1};
      ((float2*)wd)[1] = float2{a2, a3};
      ((float2*)wd)[2] = float2{a4, a5};
      ((float2*)wd)[3] = float2{a6, a7};
    }
  }

  // ---- wave-uniform weights/biases (compiler -> SGPR) ----
  float u1r[8][8];
#pragma unroll
  for (int i = 0; i < 8; i += 2) {
    float4 r0 = ((const float4*)U1)[i * 2 + 0];
    float4 r1 = ((const float4*)U1)[i * 2 + 1];
    float4 r2 = ((const float4*)U1)[i * 2 + 2];
    float4 r3 = ((const float4*)U1)[i * 2 + 3];
    u1r[i][0] = r0.x; u1r[i][1] = r0.y; u1r[i][2] = r0.z; u1r[i][3] = r0.w;
    u1r[i][4] = r1.x; u1r[i][5] = r1.y; u1r[i][6] = r1.z; u1r[i][7] = r1.w;
    u1r[i+1][0] = r2.x; u1r[i+1][1] = r2.y; u1r[i+1][2] = r2.z; u1r[i+1][3] = r2.w;
    u1r[i+1][4] = r3.x; u1r[i+1][5] = r3.y; u1r[i+1][6] = r3.z; u1r[i+1][7] = r3.w;
  }
  float bgv[8], Kc[8];
#pragma unroll
  for (int j = 0; j < 8; ++j) {
    bgv[j] = bg1[j];
    Kc[j] = __expf(2.f * (bg1[j] - bu1[j]));
  }
  const float zg = frcp(1.f + __expf(-zeta1[0]));
  const float ng = frcp(1.f + __expf(-nu1[0]));
  const float A = zg + ng;

  __syncthreads();

  // ---- recurrence: lane = (wl, r), fully in registers ----
  const int nact = (wp == 13) ? 112 : 224;
  if (tid < nact) {
    const int wl = tid / 112, r = tid % 112;
    const int base = r * ST + wl * 32;
    float h[8];
    {  // t = 0 (h == 0)
      const float* w0p = &wxs[base];
#pragma unroll
      for (int j = 0; j < 8; ++j) {
        float s = __expf(-(w0p[j] + bgv[j]));
        float z = frcp(1.f + s);
        float u = s * s * Kc[j];
        float c = fmaf(2.f, frcp(1.f + u), -1.f);
        float m = fmaf(-zg, z, A);
        h[j] = m * c;
      }
    }
#pragma unroll
    for (int t = 1; t < 8; ++t) {
      const float* wtp = &wxs[base + t * 8];
      float qa[8];
#pragma unroll
      for (int j = 0; j < 8; ++j) {
        float q = u1r[0][j] * h[0];
        q = fmaf(u1r[1][j], h[1], q);
        q = fmaf(u1r[2][j], h[2], q);
        q = fmaf(u1r[3][j], h[3], q);
        q = fmaf(u1r[4][j], h[4], q);
        q = fmaf(u1r[5][j], h[5], q);
        q = fmaf(u1r[6][j], h[6], q);
        q = fmaf(u1r[7][j], h[7], q);
        qa[j] = q;
      }
#pragma unroll
      for (int j = 0; j < 8; ++j) {
        float pre = wtp[j] + qa[j];
        float s = __expf(-(pre + bgv[j]));
        float z = frcp(1.f + s);
        float u = s * s * Kc[j];
        float c = fmaf(2.f, frcp(1.f + u), -1.f);
        float m = fmaf(-zg, z, A);
        h[j] = fmaf(z, h[j], m * c);
      }
    }
    float* dst = (isrow ? hrowg : hcolg) +
                 ((size_t)(b * 27 + 2 * wp + wl) * 112 + r) * 8;
    ((float4*)dst)[0] = float4{h[0], h[1], h[2], h[3]};
    ((float4*)dst)[1] = float4{h[4], h[5], h[6], h[7]};
  }
}

// ---------------- Kernel B: level-2, 2 patches (packed) per wave ----------------
__global__ __launch_bounds__(256) void l2_kernel(
    const float* __restrict__ hrowg, const float* __restrict__ hcolg,
    const float* __restrict__ W2, const float* __restrict__ U2,
    const float* __restrict__ bg2, const float* __restrict__ bu2,
    const float* __restrict__ zeta2, const float* __restrict__ nu2,
    float* __restrict__ out) {
  constexpr int GST = 18;  // h2 branch stride (v2 units)
  constexpr int WHT = 18;  // wh row stride (v2 units)
  __shared__ v2f hbI[PPB][128];
  __shared__ v2f whb[PPB][2 * 8 * WHT];
  __shared__ v2f h2I[PPB][3 * GST + 16];

  const int tid = threadIdx.x, wv = tid >> 6, lane = tid & 63;
  const int w = blockIdx.x * PPB + wv;
  const int n0 = 2 * w, n1 = n0 + 1;

  {
    const int p = lane >> 5, half = (lane >> 4) & 1, idx = lane & 15;
    const int pn = p ? n1 : n0;
    const int pw = pn % 27;
    const int qq = pn / 27;
    const int ph = qq % 27, bb = qq / 27;
    const float* src = half ? &hcolg[(((size_t)(bb * 27 + ph)) * 112 + pw * 4) * 8]
                            : &hrowg[(((size_t)(bb * 27 + pw)) * 112 + ph * 4) * 8];
    float4 val = ((const float4*)src)[idx];
    float* base = (float*)&hbI[wv][half * 64 + idx * 4];
    base[0 + p] = val.x;
    base[2 + p] = val.y;
    base[4 + p] = val.z;
    base[6 + p] = val.w;
  }
  __builtin_amdgcn_wave_barrier();

  const int g = lane >> 4, j = lane & 15;
  v2f w2b[8], u2b[16];
#pragma unroll
  for (int d = 0; d < 8; ++d) w2b[d] = bc(W2[d * 16 + j]);
#pragma unroll
  for (int i = 0; i < 16; ++i) u2b[i] = bc(U2[i * 16 + j]);
  const float bg2v = bg2[j], bu2v = bu2[j];
  const float zg2 = frcp(1.f + __expf(-zeta2[0]));
  const float ng2 = frcp(1.f + __expf(-nu2[0]));
  const v2f bgB = bc(bg2v);
  const v2f KB = bc(__expf(2.f * (bg2v - bu2v)));
  const v2f nzgB = bc(-zg2);
  const v2f AB = bc(zg2 + ng2);

  const int src = g >> 1;

  {
    const v2f* hb = &hbI[wv][src * 64];
    const int t0 = (g & 1) * 4;
#pragma unroll
    for (int i = 0; i < 4; ++i) {
      const int t = t0 + i;
      const v2f* hr = &hb[t * 8];
      v2f p = vmul2(hr[0], w2b[0]);
#pragma unroll
      for (int d = 1; d < 8; ++d) p = vfma2(hr[d], w2b[d], p);
      whb[wv][(src * 8 + t) * WHT + j] = p;
    }
  }
  __builtin_amdgcn_wave_barrier();

  const v2f* whsrc = &whb[wv][src * 8 * WHT];
  v2f* h2q = &h2I[wv][g * GST];

  v2f h2 = bc(0.f);
  {
    const int tt = (g & 1) ? 7 : 0;
    v2f p = whsrc[tt * WHT + j];
    h2 = gate2(p, h2, bgB, KB, nzgB, AB, true);
    h2q[j] = h2;
  }
  __builtin_amdgcn_wave_barrier();
#pragma unroll
  for (int t = 1; t < 8; ++t) {
    const int tt = (g & 1) ? (7 - t) : t;
    v2f p = whsrc[tt * WHT + j];
    const float4* q4 = (const float4*)h2q;
    float4 v0 = q4[0], v1 = q4[1], v2_ = q4[2], v3 = q4[3];
    float4 v4 = q4[4], v5 = q4[5], v6 = q4[6], v7 = q4[7];
    v2f q = vmul2(v2f{v0.x, v0.y}, u2b[0]);
    q = vfma2(v2f{v0.z, v0.w}, u2b[1], q);
    q = vfma2(v2f{v1.x, v1.y}, u2b[2], q);
    q = vfma2(v2f{v1.z, v1.w}, u2b[3], q);
    q = vfma2(v2f{v2_.x, v2_.y}, u2b[4], q);
    q = vfma2(v2f{v2_.z, v2_.w}, u2b[5], q);
    q = vfma2(v2f{v3.x, v3.y}, u2b[6], q);
    q = vfma2(v2f{v3.z, v3.w}, u2b[7], q);
    q = vfma2(v2f{v4.x, v4.y}, u2b[8], q);
    q = vfma2(v2f{v4.z, v4.w}, u2b[9], q);
    q = vfma2(v2f{v5.x, v5.y}, u2b[10], q);
    q = vfma2(v2f{v5.z, v5.w}, u2b[11], q);
    q = vfma2(v2f{v6.x, v6.y}, u2b[12], q);
    q = vfma2(v2f{v6.z, v6.w}, u2b[13], q);
    q = vfma2(v2f{v7.x, v7.y}, u2b[14], q);
    q = vfma2(v2f{v7.z, v7.w}, u2b[15], q);
    v2f pre = vadd2(p, q);
    h2 = gate2(pre, h2, bgB, KB, nzgB, AB, false);
    if (t < 7) {
      h2q[j] = h2;
      __builtin_amdgcn_wave_barrier();
    }
  }

  out[(size_t)n0 * 64 + lane] = h2.x;
  out[(size_t)n1 * 64 + lane] = h2.y;
}

extern "C" void kernel_launch(void* const* d_in, const int* in_sizes, int n_in,
                              void* d_out, int out_size, void* d_ws, size_t ws_size,
                              hipStream_t stream) {
  const float* inp   = (const float*)d_in[0];
  const float* W1    = (const float*)d_in[1];
  const float* U1    = (const float*)d_in[2];
  const float* bg1   = (const float*)d_in[3];
  const float* bu1   = (const float*)d_in[4];
  const float* zeta1 = (const float*)d_in[5];
  const float* nu1   = (const float*)d_in[6];
  const float* W2    = (const float*)d_in[7];
  const float* U2    = (const float*)d_in[8];
  const float* bg2   = (const float*)d_in[9];
  const float* bu2   = (const float*)d_in[10];
  const float* zeta2 = (const float*)d_in[11];
  const float* nu2   = (const float*)d_in[12];
  float* out = (float*)d_out;

  const size_t HSZ = (size_t)32 * 27 * 112 * 8;  // floats per h buffer
  float* hrowg = (float*)d_ws;
  float* hcolg = hrowg + HSZ;

  // Kernel A: 2 modes x 32 b x 14 window-pairs = 896 blocks
  l1_kernel<<<dim3(896), dim3(256), 0, stream>>>(
      inp, W1, U1, bg1, bu1, zeta1, nu1, hrowg, hcolg);
  // Kernel B: 11664 patch-pair waves, 4/block
  l2_kernel<<<dim3(2916), dim3(256), 0, stream>>>(
      hrowg, hcolg, W2, U2, bg2, bu2, zeta2, nu2, out);
}